// Round 3
// baseline (254.337 us; speedup 1.0000x reference)
//
#include <hip/hip_runtime.h>

#define B_ 4
#define S_ 2048
#define HIDN 512
#define NH 8
#define DH 64

typedef __attribute__((ext_vector_type(8))) short short8;
typedef __attribute__((ext_vector_type(8))) __bf16 bf16x8;
typedef __attribute__((ext_vector_type(4))) float floatx4;

__device__ inline short f2bf(float f) {
    union { float f; unsigned u; } x; x.f = f;
    unsigned r = x.u + 0x7fffu + ((x.u >> 16) & 1u);   // RTNE bf16
    return (short)(r >> 16);
}

// load 8 fp32, convert to 8 bf16 packed in short8
__device__ inline short8 cvt8(const float* __restrict__ p) {
    floatx4 f0 = *(const floatx4*)p;
    floatx4 f1 = *(const floatx4*)(p + 4);
    short8 r;
    r[0] = f2bf(f0[0]); r[1] = f2bf(f0[1]); r[2] = f2bf(f0[2]); r[3] = f2bf(f0[3]);
    r[4] = f2bf(f1[0]); r[5] = f2bf(f1[1]); r[6] = f2bf(f1[2]); r[7] = f2bf(f1[3]);
    return r;
}

// MFMA with short8 register fragments (bit-cast in-register only)
__device__ inline floatx4 mfma_s(short8 a, short8 b, floatx4 c) {
    return __builtin_amdgcn_mfma_f32_16x16x32_bf16(
        __builtin_bit_cast(bf16x8, a), __builtin_bit_cast(bf16x8, b), c, 0, 0, 0);
}

// ---------------------------------------------------------------------------
// GEMM: C[m][n] = sum_k X[m][k] * W[n][k].  M=8192, N=K=512.
// 128x128 tile, BK=32, 4 waves of 64x64. X: fp32 (MODE 0/1) or bf16 (MODE 2);
// W: fp32 always, converted to bf16 at staging. Accum fp32.
// MODE 0: C bf16, head layout (B,NH,S,DH)    (Q, K)
// MODE 1: C bf16, transposed (B,NH,DH,S)     (V)
// MODE 2: C fp32, row-major (M,HIDN)         (final out)
// ---------------------------------------------------------------------------
template<int MODE, typename XT, typename CT>
__global__ __launch_bounds__(256) void gemm_bt(const XT* __restrict__ X,
                                               const float* __restrict__ W,
                                               CT* __restrict__ C) {
    const int K = HIDN;
    __shared__ __align__(16) short Als[128][40];  // pad 32->40 (2-way, free)
    __shared__ __align__(16) short Bls[128][40];

    const int t = threadIdx.x;
    const int w = t >> 6, lane = t & 63, quad = lane >> 4, l16 = lane & 15;
    const int wm = (w & 1) * 64, wn = (w >> 1) * 64;
    const int m0 = blockIdx.x * 128, n0 = blockIdx.y * 128;

    floatx4 acc[4][4];
    floatx4 zero = {0.f, 0.f, 0.f, 0.f};
#pragma unroll
    for (int i = 0; i < 4; i++)
#pragma unroll
        for (int j = 0; j < 4; j++) acc[i][j] = zero;

    const int row0 = t >> 2;        // 0..63
    const int c8 = (t & 3) * 8;     // 0,8,16,24

    for (int k0 = 0; k0 < K; k0 += 32) {
        __syncthreads();
        if constexpr (sizeof(XT) == 4) {
            *(short8*)&Als[row0][c8]    = cvt8(&X[(m0 + row0) * K + k0 + c8]);
            *(short8*)&Als[row0+64][c8] = cvt8(&X[(m0 + row0 + 64) * K + k0 + c8]);
        } else {
            *(short8*)&Als[row0][c8]    = *(const short8*)&X[(m0 + row0) * K + k0 + c8];
            *(short8*)&Als[row0+64][c8] = *(const short8*)&X[(m0 + row0 + 64) * K + k0 + c8];
        }
        *(short8*)&Bls[row0][c8]    = cvt8(&W[(n0 + row0) * K + k0 + c8]);
        *(short8*)&Bls[row0+64][c8] = cvt8(&W[(n0 + row0 + 64) * K + k0 + c8]);
        __syncthreads();

        short8 a[4], b[4];
#pragma unroll
        for (int i = 0; i < 4; i++) a[i] = *(const short8*)&Als[wm + i*16 + l16][quad*8];
#pragma unroll
        for (int j = 0; j < 4; j++) b[j] = *(const short8*)&Bls[wn + j*16 + l16][quad*8];
#pragma unroll
        for (int i = 0; i < 4; i++)
#pragma unroll
            for (int j = 0; j < 4; j++)
                acc[i][j] = mfma_s(a[i], b[j], acc[i][j]);
    }

#pragma unroll
    for (int i = 0; i < 4; i++)
#pragma unroll
        for (int j = 0; j < 4; j++)
#pragma unroll
            for (int r = 0; r < 4; r++) {
                int m = m0 + wm + i*16 + quad*4 + r;   // C row = quad*4+reg
                int n = n0 + wn + j*16 + l16;          // C col = lane&15
                if constexpr (MODE == 2) {
                    C[m * HIDN + n] = acc[i][j][r];    // fp32 store
                } else {
                    short v = f2bf(acc[i][j][r]);
                    int bb = m >> 11, s = m & 2047, h = n >> 6, d = n & 63;
                    if constexpr (MODE == 0)
                        C[((bb * NH + h) * S_ + s) * DH + d] = v;
                    else
                        C[((bb * NH + h) * DH + d) * S_ + s] = v;
                }
            }
}

// ---------------------------------------------------------------------------
// Flash attention. Block = 256 thr (4 waves): (b, h, 64 q-rows); each wave
// owns 16 q-rows. KV tiles of 128 keys, online softmax, P via LDS transform.
// Qh, Kh: (B,NH,S,DH) bf16   VT: (B,NH,DH,S) bf16   AO: (B,S,HIDN) bf16
// ---------------------------------------------------------------------------
__global__ __launch_bounds__(256) void attn_kernel(const short* __restrict__ Qh,
                                                   const short* __restrict__ Kh,
                                                   const short* __restrict__ VT,
                                                   const int* __restrict__ vlen,
                                                   short* __restrict__ AO) {
    __shared__ __align__(16) short Kls[128][72];    // [key][d], pad 64->72
    __shared__ __align__(16) short Vls[64][136];    // [d][key], pad 128->136
    __shared__ __align__(16) short Pls[4][16][136]; // per-wave [qrow][key]

    const int t = threadIdx.x, w = t >> 6, lane = t & 63;
    const int quad = lane >> 4, l16 = lane & 15;
    const int qb = blockIdx.x * 64;
    const int h = blockIdx.y, b = blockIdx.z;
    const int bh = b * NH + h;
    const int vl = vlen[b];
    const int ntiles = (vl + 127) >> 7;   // block-uniform (per-b)

    // Q fragments (A-layout): m = lane&15, k = quad*8+j
    const short* qrow = &Qh[(bh * S_ + qb + w * 16 + l16) * DH];
    short8 qa0 = *(const short8*)&qrow[quad * 8];
    short8 qa1 = *(const short8*)&qrow[32 + quad * 8];

    float m_run[4], l_run[4];
    floatx4 Oacc[4];
    floatx4 zero = {0.f, 0.f, 0.f, 0.f};
#pragma unroll
    for (int r = 0; r < 4; r++) { m_run[r] = -1e30f; l_run[r] = 0.f; }
#pragma unroll
    for (int dt = 0; dt < 4; dt++) Oacc[dt] = zero;

    for (int kt = 0; kt < ntiles; kt++) {
        const int base = kt << 7;
        __syncthreads();   // prev iter's PV reads done before restaging
        {   // stage K tile: 128 keys x 64 dims
            const short* Kg = &Kh[(bh * S_ + base) * DH];
#pragma unroll
            for (int it = 0; it < 4; it++) {
                int idx = it * 256 + t;
                int row = idx >> 3, cc = (idx & 7) * 8;
                *(short8*)&Kls[row][cc] = *(const short8*)&Kg[row * DH + cc];
            }
            // stage V^T tile: 64 dims x 128 keys
            const short* Vg = &VT[bh * DH * S_ + base];
#pragma unroll
            for (int it = 0; it < 4; it++) {
                int idx = it * 256 + t;
                int d = idx >> 4, cc = (idx & 15) * 8;
                *(short8*)&Vls[d][cc] = *(const short8*)&Vg[d * S_ + cc];
            }
        }
        __syncthreads();

        // scores: S[m][key] = sum_d Q[m][d] K[key][d], 8 key-tiles of 16
        floatx4 sc[8];
#pragma unroll
        for (int n = 0; n < 8; n++) {
            short8 kb0 = *(const short8*)&Kls[n * 16 + l16][quad * 8];
            short8 kb1 = *(const short8*)&Kls[n * 16 + l16][32 + quad * 8];
            floatx4 s = zero;
            s = mfma_s(qa0, kb0, s);
            s = mfma_s(qa1, kb1, s);
            sc[n] = s;
        }
        // scale 1/sqrt(DH)=0.125 + mask (key >= vl -> -1e6, matches ref NEG)
#pragma unroll
        for (int n = 0; n < 8; n++) {
            int key = base + n * 16 + l16;
            bool valid = key < vl;
#pragma unroll
            for (int r = 0; r < 4; r++)
                sc[n][r] = valid ? sc[n][r] * 0.125f : -1e6f;
        }
        // online softmax: C row = quad*4+r; its 16 cols live in quad's lanes
        float mx[4];
#pragma unroll
        for (int r = 0; r < 4; r++) {
            float v = sc[0][r];
#pragma unroll
            for (int n = 1; n < 8; n++) v = fmaxf(v, sc[n][r]);
            v = fmaxf(v, __shfl_xor(v, 1));
            v = fmaxf(v, __shfl_xor(v, 2));
            v = fmaxf(v, __shfl_xor(v, 4));
            v = fmaxf(v, __shfl_xor(v, 8));
            mx[r] = v;
        }
        float alpha[4];
#pragma unroll
        for (int r = 0; r < 4; r++) {
            float mn = fmaxf(m_run[r], mx[r]);
            alpha[r] = __expf(m_run[r] - mn);   // first tile: exp(-1e30)=0
            m_run[r] = mn;
        }
#pragma unroll
        for (int r = 0; r < 4; r++) {
            float s = 0.f;
#pragma unroll
            for (int n = 0; n < 8; n++) {
                float p = __expf(sc[n][r] - m_run[r]);  // masked: underflow to 0
                sc[n][r] = p;
                s += p;
            }
            s += __shfl_xor(s, 1);
            s += __shfl_xor(s, 2);
            s += __shfl_xor(s, 4);
            s += __shfl_xor(s, 8);
            l_run[r] = l_run[r] * alpha[r] + s;
        }
#pragma unroll
        for (int dt = 0; dt < 4; dt++)
#pragma unroll
            for (int r = 0; r < 4; r++) Oacc[dt][r] *= alpha[r];

        // P: C-layout -> LDS -> A-layout (barrier makes ordering explicit)
#pragma unroll
        for (int n = 0; n < 8; n++)
#pragma unroll
            for (int r = 0; r < 4; r++)
                Pls[w][quad * 4 + r][n * 16 + l16] = f2bf(sc[n][r]);

        __syncthreads();

        // O += P @ V : contraction over 128 keys (4 MFMA k-steps)
#pragma unroll
        for (int kk = 0; kk < 4; kk++) {
            short8 pa = *(const short8*)&Pls[w][l16][kk * 32 + quad * 8];
#pragma unroll
            for (int dt = 0; dt < 4; dt++) {
                short8 vb = *(const short8*)&Vls[dt * 16 + l16][kk * 32 + quad * 8];
                Oacc[dt] = mfma_s(pa, vb, Oacc[dt]);
            }
        }
    }

    // epilogue: O /= l, write bf16 to (B,S,HIDN)
#pragma unroll
    for (int dt = 0; dt < 4; dt++)
#pragma unroll
        for (int r = 0; r < 4; r++) {
            int q = qb + w * 16 + quad * 4 + r;
            int col = h * DH + dt * 16 + l16;
            float o = Oacc[dt][r] / l_run[r];
            AO[(b * S_ + q) * HIDN + col] = f2bf(o);
        }
}

extern "C" void kernel_launch(void* const* d_in, const int* in_sizes, int n_in,
                              void* d_out, int out_size, void* d_ws, size_t ws_size,
                              hipStream_t stream) {
    const float* q  = (const float*)d_in[0];
    const float* k  = (const float*)d_in[1];
    const float* v  = (const float*)d_in[2];
    const int*   vl = (const int*)d_in[3];
    const float* wq = (const float*)d_in[4];
    const float* wk = (const float*)d_in[5];
    const float* wv = (const float*)d_in[6];
    const float* wo = (const float*)d_in[7];
    float* out = (float*)d_out;

    const size_t HSZ = (size_t)B_ * NH * S_ * DH;  // 4.19M elements (bf16)
    short* Qh = (short*)d_ws;
    short* Kh = Qh + HSZ;
    short* VT = Kh + HSZ;
    short* AO = VT + HSZ;

    dim3 blk(256);
    dim3 gproj(64, 4, 1);
    gemm_bt<0, float, short><<<gproj, blk, 0, stream>>>(q, wq, Qh);
    gemm_bt<0, float, short><<<gproj, blk, 0, stream>>>(k, wk, Kh);
    gemm_bt<1, float, short><<<gproj, blk, 0, stream>>>(v, wv, VT);
    attn_kernel<<<dim3(S_ / 64, NH, B_), blk, 0, stream>>>(Qh, Kh, VT, vl, AO);
    gemm_bt<2, short, float><<<gproj, blk, 0, stream>>>(AO, wo, out);
}

// Round 4
// 183.352 us; speedup vs baseline: 1.3872x; 1.3872x over previous
//
#include <hip/hip_runtime.h>

#define B_ 4
#define S_ 2048
#define HIDN 512
#define NH 8
#define DH 64

typedef __attribute__((ext_vector_type(8))) short short8;
typedef __attribute__((ext_vector_type(4))) short short4v;
typedef __attribute__((ext_vector_type(8))) __bf16 bf16x8;
typedef __attribute__((ext_vector_type(4))) float floatx4;
typedef __attribute__((ext_vector_type(2))) unsigned uint2v;

__device__ inline short f2bf(float f) {            // RTNE
    union { float f; unsigned u; } x; x.f = f;
    unsigned r = x.u + 0x7fffu + ((x.u >> 16) & 1u);
    return (short)(r >> 16);
}

// pack two floats -> two bf16 (round-half-up) in one uint via v_perm
__device__ inline unsigned pack2(float a, float b) {
    unsigned ua = __builtin_bit_cast(unsigned, a) + 0x8000u;
    unsigned ub = __builtin_bit_cast(unsigned, b) + 0x8000u;
    return __builtin_amdgcn_perm(ub, ua, 0x07060302);  // [ua.hi16, ub.hi16]
}

__device__ inline short8 cvt8(const float* __restrict__ p) {
    floatx4 f0 = *(const floatx4*)p;
    floatx4 f1 = *(const floatx4*)(p + 4);
    short8 r;
    r[0] = f2bf(f0[0]); r[1] = f2bf(f0[1]); r[2] = f2bf(f0[2]); r[3] = f2bf(f0[3]);
    r[4] = f2bf(f1[0]); r[5] = f2bf(f1[1]); r[6] = f2bf(f1[2]); r[7] = f2bf(f1[3]);
    return r;
}

__device__ inline floatx4 mfma_s(short8 a, short8 b, floatx4 c) {
    return __builtin_amdgcn_mfma_f32_16x16x32_bf16(
        __builtin_bit_cast(bf16x8, a), __builtin_bit_cast(bf16x8, b), c, 0, 0, 0);
}

__device__ inline float vmax4(floatx4 v) {
    return fmaxf(fmaxf(v[0], v[1]), fmaxf(v[2], v[3]));
}

// ---------------------------------------------------------------------------
// Pre-convert Wq,Wk,Wv (fp32 -> bf16). grid (256,3) x 256 thr, 4 elem/thr.
// ---------------------------------------------------------------------------
__global__ void cvt_w(const float* __restrict__ wq, const float* __restrict__ wk,
                      const float* __restrict__ wv, short* __restrict__ out) {
    const float* src = blockIdx.y == 0 ? wq : (blockIdx.y == 1 ? wk : wv);
    int i = (blockIdx.x * 256 + threadIdx.x) * 4;
    floatx4 f = *(const floatx4*)&src[i];
    short4v v; v[0]=f2bf(f[0]); v[1]=f2bf(f[1]); v[2]=f2bf(f[2]); v[3]=f2bf(f[3]);
    *(short4v*)&out[blockIdx.y * (HIDN * HIDN) + i] = v;
}

// ---------------------------------------------------------------------------
// Fused QKV projection. grid (64,4,3); z=0:Q, z=1:K (head layout), z=2:V^T.
// X fp32 (cvt in staging), W bf16 (pre-converted). 128x128 tile, BK=32.
// ---------------------------------------------------------------------------
__global__ __launch_bounds__(256) void gemm_qkv(const float* __restrict__ xq,
                                                const float* __restrict__ xk,
                                                const float* __restrict__ xv,
                                                const short* __restrict__ wb,
                                                short* __restrict__ Qh,
                                                short* __restrict__ Kh,
                                                short* __restrict__ VT) {
    const int z = blockIdx.z;
    const float* X = z == 0 ? xq : (z == 1 ? xk : xv);
    const short* W = wb + z * (HIDN * HIDN);
    short* dstQK = z == 0 ? Qh : Kh;

    __shared__ __align__(16) short Als[128][40];
    __shared__ __align__(16) short Bls[128][40];

    const int t = threadIdx.x;
    const int w = t >> 6, lane = t & 63, quad = lane >> 4, l16 = lane & 15;
    const int wm = (w & 1) * 64, wn = (w >> 1) * 64;
    const int m0 = blockIdx.x * 128, n0 = blockIdx.y * 128;

    floatx4 acc[4][4];
    floatx4 zero = {0.f, 0.f, 0.f, 0.f};
#pragma unroll
    for (int i = 0; i < 4; i++)
#pragma unroll
        for (int j = 0; j < 4; j++) acc[i][j] = zero;

    const int row0 = t >> 2, c8 = (t & 3) * 8;

    for (int k0 = 0; k0 < HIDN; k0 += 32) {
        __syncthreads();
        *(short8*)&Als[row0][c8]    = cvt8(&X[(m0 + row0) * HIDN + k0 + c8]);
        *(short8*)&Als[row0+64][c8] = cvt8(&X[(m0 + row0 + 64) * HIDN + k0 + c8]);
        *(short8*)&Bls[row0][c8]    = *(const short8*)&W[(n0 + row0) * HIDN + k0 + c8];
        *(short8*)&Bls[row0+64][c8] = *(const short8*)&W[(n0 + row0 + 64) * HIDN + k0 + c8];
        __syncthreads();

        short8 a[4], b[4];
#pragma unroll
        for (int i = 0; i < 4; i++) a[i] = *(const short8*)&Als[wm + i*16 + l16][quad*8];
#pragma unroll
        for (int j = 0; j < 4; j++) b[j] = *(const short8*)&Bls[wn + j*16 + l16][quad*8];
#pragma unroll
        for (int i = 0; i < 4; i++)
#pragma unroll
            for (int j = 0; j < 4; j++)
                acc[i][j] = mfma_s(a[i], b[j], acc[i][j]);
    }

    if (z < 2) {   // head layout (B,NH,S,DH), scalar b16 stores
#pragma unroll
        for (int i = 0; i < 4; i++)
#pragma unroll
            for (int j = 0; j < 4; j++)
#pragma unroll
                for (int r = 0; r < 4; r++) {
                    int m = m0 + wm + i*16 + quad*4 + r;
                    int n = n0 + wn + j*16 + l16;
                    int bb = m >> 11, s = m & 2047, h = n >> 6, d = n & 63;
                    dstQK[((bb * NH + h) * S_ + s) * DH + d] = f2bf(acc[i][j][r]);
                }
    } else {       // V^T (B,NH,DH,S): r-dim is contiguous s -> packed b64
#pragma unroll
        for (int i = 0; i < 4; i++)
#pragma unroll
            for (int j = 0; j < 4; j++) {
                int s0 = m0 + wm + i*16 + quad*4;
                int n = n0 + wn + j*16 + l16;
                int bb = s0 >> 11, s = s0 & 2047, h = n >> 6, d = n & 63;
                unsigned lo = pack2(acc[i][j][0], acc[i][j][1]);
                unsigned hi = pack2(acc[i][j][2], acc[i][j][3]);
                uint2v v; v[0] = lo; v[1] = hi;
                *(uint2v*)&VT[((bb * NH + h) * DH + d) * S_ + s] = v;
            }
    }
}

// ---------------------------------------------------------------------------
// Out projection: C[m][n] = sum_k AO[m][k] * Wo[n][k]. 128x64 tile, grid(64,8).
// AO bf16, Wo fp32 (cvt in staging), out fp32.
// ---------------------------------------------------------------------------
__global__ __launch_bounds__(256) void gemm_out(const short* __restrict__ AO,
                                                const float* __restrict__ Wo,
                                                float* __restrict__ C) {
    __shared__ __align__(16) short Als[128][40];
    __shared__ __align__(16) short Bls[64][40];

    const int t = threadIdx.x;
    const int w = t >> 6, lane = t & 63, quad = lane >> 4, l16 = lane & 15;
    const int wm = (w & 1) * 64, wn = (w >> 1) * 32;
    const int m0 = blockIdx.x * 128, n0 = blockIdx.y * 64;

    floatx4 acc[4][2];
    floatx4 zero = {0.f, 0.f, 0.f, 0.f};
#pragma unroll
    for (int i = 0; i < 4; i++)
#pragma unroll
        for (int j = 0; j < 2; j++) acc[i][j] = zero;

    const int row0 = t >> 2, c8 = (t & 3) * 8;

    for (int k0 = 0; k0 < HIDN; k0 += 32) {
        __syncthreads();
        *(short8*)&Als[row0][c8]    = *(const short8*)&AO[(m0 + row0) * HIDN + k0 + c8];
        *(short8*)&Als[row0+64][c8] = *(const short8*)&AO[(m0 + row0 + 64) * HIDN + k0 + c8];
        *(short8*)&Bls[row0][c8]    = cvt8(&Wo[(n0 + row0) * HIDN + k0 + c8]);
        __syncthreads();

        short8 a[4], b[2];
#pragma unroll
        for (int i = 0; i < 4; i++) a[i] = *(const short8*)&Als[wm + i*16 + l16][quad*8];
#pragma unroll
        for (int j = 0; j < 2; j++) b[j] = *(const short8*)&Bls[wn + j*16 + l16][quad*8];
#pragma unroll
        for (int i = 0; i < 4; i++)
#pragma unroll
            for (int j = 0; j < 2; j++)
                acc[i][j] = mfma_s(a[i], b[j], acc[i][j]);
    }

#pragma unroll
    for (int i = 0; i < 4; i++)
#pragma unroll
        for (int j = 0; j < 2; j++)
#pragma unroll
            for (int r = 0; r < 4; r++) {
                int m = m0 + wm + i*16 + quad*4 + r;
                int n = n0 + wn + j*16 + l16;
                C[m * HIDN + n] = acc[i][j][r];
            }
}

// ---------------------------------------------------------------------------
// Flash attention, transposed orientation. Block = 4 waves, (b,h,64 q).
// S^T = K·Q^T  (lane owns one q-column -> lane-scalar softmax state);
// O^T = V^T·P^T. XOR-swizzled LDS; P overlays K region (32 KB -> 5 blk/CU).
// ---------------------------------------------------------------------------
__global__ __launch_bounds__(256, 4) void attn_kernel(const short* __restrict__ Qh,
                                                      const short* __restrict__ Kh,
                                                      const short* __restrict__ VT,
                                                      const int* __restrict__ vlen,
                                                      short* __restrict__ AO) {
    __shared__ __align__(16) short Ksh[128 * 64];   // K tile; overlaid by P
    __shared__ __align__(16) short Vsh[64 * 128];   // V^T tile
    short* Psh = Ksh;                                // wave w region: w*2048 shorts

    const int t = threadIdx.x, w = t >> 6, lane = t & 63;
    const int quad = lane >> 4, l16 = lane & 15;
    const int qb = blockIdx.x * 64;
    const int h = blockIdx.y, b = blockIdx.z;
    const int bh = b * NH + h;
    const int vl = vlen[b];
    const int nfull = vl >> 7, rem = vl & 127;
    const int nt = nfull + (rem ? 1 : 0);

    const float SC = 0.180336879f;                   // 0.125 * log2(e)

    // Q as B-operand: lane l16 = q, k = quad*8+j
    const short* qrow = &Qh[(bh * S_ + qb + w * 16 + l16) * DH];
    short8 qa0 = *(const short8*)&qrow[quad * 8];
    short8 qa1 = *(const short8*)&qrow[32 + quad * 8];

    float m_run = -1e30f, l_run = 0.f;
    floatx4 Oacc[4];
    floatx4 zero = {0.f, 0.f, 0.f, 0.f};
#pragma unroll
    for (int dt = 0; dt < 4; dt++) Oacc[dt] = zero;

    for (int kt = 0; kt < nt; kt++) {
        const int base = kt << 7;
        const bool bnd = (base + 128) > vl;
        __syncthreads();                             // prev PV reads done
        {
            const short* Kg = &Kh[(bh * S_ + base) * DH];
#pragma unroll
            for (int it = 0; it < 4; it++) {
                int idx = it * 256 + t;
                int row = idx >> 3, c = idx & 7;
                *(short8*)&Ksh[row * 64 + (((c ^ (row & 7))) << 3)] =
                    *(const short8*)&Kg[row * DH + (c << 3)];
            }
            const short* Vg = &VT[bh * DH * S_ + base];
#pragma unroll
            for (int it = 0; it < 4; it++) {
                int idx = it * 256 + t;
                int d = idx >> 4, c = idx & 15;
                *(short8*)&Vsh[d * 128 + (((c ^ (d & 7))) << 3)] =
                    *(const short8*)&Vg[d * S_ + (c << 3)];
            }
        }
        __syncthreads();                             // staging visible

        // S^T: rows = key (quad*4+r within n*16), col = q (l16)
        floatx4 sc[8];
#pragma unroll
        for (int n = 0; n < 8; n++) {
            int krow = n * 16 + l16;
            const short* kr = &Ksh[krow * 64];
            short8 kb0 = *(const short8*)&kr[((quad ^ (krow & 7)) << 3)];
            short8 kb1 = *(const short8*)&kr[(((4 + quad) ^ (krow & 7)) << 3)];
            floatx4 s = zero;
            s = mfma_s(kb0, qa0, s);
            s = mfma_s(kb1, qa1, s);
            sc[n] = s;
        }
        __syncthreads();                             // all Ksh reads done (P overlay)

        if (!bnd) {
#pragma unroll
            for (int n = 0; n < 8; n++)
#pragma unroll
                for (int r = 0; r < 4; r++) sc[n][r] *= SC;
        } else {
#pragma unroll
            for (int n = 0; n < 8; n++)
#pragma unroll
                for (int r = 0; r < 4; r++) {
                    int key = base + n * 16 + quad * 4 + r;
                    sc[n][r] = (key < vl) ? sc[n][r] * SC : -1e30f;
                }
        }

        // softmax (exp2 domain), per-lane q-column + 2 shuffles
        float mx = vmax4(sc[0]);
#pragma unroll
        for (int n = 1; n < 8; n++) mx = fmaxf(mx, vmax4(sc[n]));
        mx = fmaxf(mx, __shfl_xor(mx, 16));
        mx = fmaxf(mx, __shfl_xor(mx, 32));
        float mnew = fmaxf(m_run, mx);
        float alpha = __builtin_amdgcn_exp2f(m_run - mnew);
        m_run = mnew;
        float rs = 0.f;
#pragma unroll
        for (int n = 0; n < 8; n++)
#pragma unroll
            for (int r = 0; r < 4; r++) {
                float p = __builtin_amdgcn_exp2f(sc[n][r] - mnew);
                sc[n][r] = p;
                rs += p;
            }
        rs += __shfl_xor(rs, 16);
        rs += __shfl_xor(rs, 32);
        l_run = l_run * alpha + rs;
#pragma unroll
        for (int dt = 0; dt < 4; dt++)
#pragma unroll
            for (int r = 0; r < 4; r++) Oacc[dt][r] *= alpha;   // alpha lane-uniform

        // P^T store: 4 register-rows = 4 consecutive keys -> b64 writes
#pragma unroll
        for (int n = 0; n < 8; n++) {
            unsigned lo = pack2(sc[n][0], sc[n][1]);
            unsigned hi = pack2(sc[n][2], sc[n][3]);
            int c = (n << 1) + (quad >> 1);
            int idx = (w << 11) + (l16 << 7) + ((c ^ (l16 & 7)) << 3) + ((quad & 1) << 2);
            uint2v pv; pv[0] = lo; pv[1] = hi;
            *(uint2v*)&Psh[idx] = pv;
        }
        __syncthreads();                             // P visible + ordered

        // O^T += V^T * P^T  (A = V^T rows d, B = P rows q)
#pragma unroll
        for (int kk = 0; kk < 4; kk++) {
            int pc = (kk << 2) + quad;
            short8 pf = *(const short8*)&Psh[(w << 11) + (l16 << 7) + ((pc ^ (l16 & 7)) << 3)];
#pragma unroll
            for (int dt = 0; dt < 4; dt++) {
                int vrow = dt * 16 + l16;
                short8 vf = *(const short8*)&Vsh[vrow * 128 + ((pc ^ (vrow & 7)) << 3)];
                Oacc[dt] = mfma_s(vf, pf, Oacc[dt]);
            }
        }
    }

    // epilogue: lane owns q = l16 (+base); d = dt*16 + quad*4 + r -> b64 stores
    float inv = 1.0f / l_run;
    int q = qb + w * 16 + l16;
    short* dst = &AO[(b * S_ + q) * HIDN + h * DH];
#pragma unroll
    for (int dt = 0; dt < 4; dt++) {
        unsigned lo = pack2(Oacc[dt][0] * inv, Oacc[dt][1] * inv);
        unsigned hi = pack2(Oacc[dt][2] * inv, Oacc[dt][3] * inv);
        uint2v v; v[0] = lo; v[1] = hi;
        *(uint2v*)&dst[dt * 16 + quad * 4] = v;
    }
}

extern "C" void kernel_launch(void* const* d_in, const int* in_sizes, int n_in,
                              void* d_out, int out_size, void* d_ws, size_t ws_size,
                              hipStream_t stream) {
    const float* q  = (const float*)d_in[0];
    const float* k  = (const float*)d_in[1];
    const float* v  = (const float*)d_in[2];
    const int*   vl = (const int*)d_in[3];
    const float* wq = (const float*)d_in[4];
    const float* wk = (const float*)d_in[5];
    const float* wv = (const float*)d_in[6];
    const float* wo = (const float*)d_in[7];
    float* out = (float*)d_out;

    const size_t HSZ = (size_t)B_ * NH * S_ * DH;  // 4.19M shorts each
    short* Qh = (short*)d_ws;
    short* Kh = Qh + HSZ;
    short* VT = Kh + HSZ;
    short* AO = VT + HSZ;
    short* Wb = AO;   // 3*512*512 bf16 carved from AO region (dead until attn)

    dim3 blk(256);
    cvt_w<<<dim3(256, 3), blk, 0, stream>>>(wq, wk, wv, Wb);
    gemm_qkv<<<dim3(64, 4, 3), blk, 0, stream>>>(q, k, v, Wb, Qh, Kh, VT);
    attn_kernel<<<dim3(S_ / 64, NH, B_), blk, 0, stream>>>(Qh, Kh, VT, vl, AO);
    gemm_out<<<dim3(64, 8), blk, 0, stream>>>(AO, wo, out);
}